// Round 9
// baseline (471.498 us; speedup 1.0000x reference)
//
#include <hip/hip_runtime.h>

#define N_TRACES 128
#define TLEN 32
#define IN_DIM 64
#define HID 128
#define G4 512

// ---------- helpers ----------

__device__ __forceinline__ float fast_sigmoid(float x) {
    return 1.0f / (1.0f + __expf(-x));
}
__device__ __forceinline__ float fast_tanh(float x) {
    return 1.0f - 2.0f / (__expf(2.0f * x) + 1.0f);
}
// sum over lane pairs (xor1); both lanes get the pair sum
__device__ __forceinline__ float pair_reduce(float x) {
    x += __int_as_float(__builtin_amdgcn_update_dpp(
        0, __float_as_int(x), 0xB1, 0xF, 0xF, true));
    return x;
}
// sum over quads
__device__ __forceinline__ float quad_reduce(float x) {
    x += __int_as_float(__builtin_amdgcn_update_dpp(
        0, __float_as_int(x), 0xB1, 0xF, 0xF, true));
    x += __int_as_float(__builtin_amdgcn_update_dpp(
        0, __float_as_int(x), 0x4E, 0xF, 0xF, true));
    return x;
}

// load 4 gate rows {r+128i} of W[512][ld], k-slice [SW*s, SW*s+SW)
template <int SW>
__device__ __forceinline__ void load_rows(const float* __restrict__ W, int ld,
                                          int r, int s, float (&w)[4][SW]) {
    #pragma unroll
    for (int i = 0; i < 4; ++i) {
        const float* wr = W + (size_t)(r + 128 * i) * ld + SW * s;
        #pragma unroll
        for (int j = 0; j < SW / 4; ++j) {
            float4 v = *(const float4*)(wr + 4 * j);
            w[i][4 * j + 0] = v.x; w[i][4 * j + 1] = v.y;
            w[i][4 * j + 2] = v.z; w[i][4 * j + 3] = v.w;
        }
    }
}

template <int SW>
__device__ __forceinline__ void matvec(const float (&w)[4][SW],
                                       const float* hb, float (&acc)[4]) {
    #pragma unroll
    for (int j = 0; j < SW / 4; ++j) {
        float4 v = *(const float4*)(hb + 4 * j);
        const float hx[4] = {v.x, v.y, v.z, v.w};
        #pragma unroll
        for (int e = 0; e < 4; ++e) {
            acc[0] = fmaf(w[0][4 * j + e], hx[e], acc[0]);
            acc[1] = fmaf(w[1][4 * j + e], hx[e], acc[1]);
            acc[2] = fmaf(w[2][4 * j + e], hx[e], acc[2]);
            acc[3] = fmaf(w[3][4 * j + e], hx[e], acc[3]);
        }
    }
}

// ---------- cross-layer pipelined per-trace kernel ----------
// 768 threads = 12 waves = 3 waves/SIMD. Three 256-thread groups run the three
// 512x128 matvecs of both layers CONCURRENTLY each barrier step:
//   A: h1(tau)   = lstm0(h1(tau-1), xp0(tau))
//   B: p(tau-1)  = Wih1 @ h1(tau-1) + b_ih1 + b_hh1
//   C: h2(tau-2) = lstm1(h2(tau-3), p(tau-2))
// -> 34 barrier steps instead of 96 (r6): the ~1800cyc/step overhead that
// resisted tuning (r2-r8) is amortized 3x. Each SIMD gets one A + one B + one
// C wave (balanced issue, mutual latency hiding).
// Rings padded: k-slice s at word 68*s, so each ds_read_b128's two addresses
// hit disjoint banks (r8 lesson: 2-address b128 is NOT free on same banks).

__global__ __launch_bounds__(768) void lstm_pipe(
    const float* __restrict__ input, // [4096][64]
    const float* __restrict__ Wih0,  // [512][64]
    const float* __restrict__ Whh0,  // [512][128]
    const float* __restrict__ bih0,  // [512]
    const float* __restrict__ bhh0,  // [512]
    const float* __restrict__ Wih1,  // [512][128]
    const float* __restrict__ Whh1,  // [512][128]
    const float* __restrict__ bih1,  // [512]
    const float* __restrict__ bhh1,  // [512]
    const float* __restrict__ Wlin,  // [128]
    const float* __restrict__ blin,  // [1]
    float* __restrict__ y)           // [4096]
{
    const int trace = blockIdx.x;
    const int tid = threadIdx.x;
    const int grp = tid >> 8;            // 0=A, 1=B, 2=C (wave-uniform)
    const int lt  = tid & 255;
    const int r   = lt >> 1;             // hidden unit / gate-row base, 0..127
    const int s   = lt & 1;              // k-half
    const int roff = r + 4 * (r >> 6);   // padded ring offset: k at k+4*(k>>6)

    __shared__ float xp0[TLEN * G4];     // 64 KB layer-0 input projection
    __shared__ float h2h[TLEN][132];     // h2 history (padded) ; staging for x
    __shared__ float h1r[2][136];        // h1 ring, slice s at 68s
    __shared__ float h2r[2][136];        // h2 ring
    __shared__ float pr[2][G4];          // p ring (layer-1 input projection)

    // group-specific main-loop weights: 4 rows x 64-k half
    float w[4][64];
    const float* Wm = (grp == 0) ? Whh0 : (grp == 1) ? Wih1 : Whh1;
    load_rows<64>(Wm, HID, r, s, w);

    float bi[4] = {0.f, 0.f, 0.f, 0.f};
    if (grp == 1) {
        #pragma unroll
        for (int i = 0; i < 4; ++i) bi[i] = bih1[r + 128 * i] + bhh1[r + 128 * i];
    }

    // stage x (2048 floats) into h2h region; zero the rings
    if (tid < 512) {
        const float4* src = (const float4*)(input + (size_t)trace * TLEN * IN_DIM);
        ((float4*)&h2h[0][0])[tid] = src[tid];
    }
    if (tid < 272) { (&h1r[0][0])[tid] = 0.f; (&h2r[0][0])[tid] = 0.f; }
    for (int i = tid; i < 2 * G4; i += 768) (&pr[0][0])[i] = 0.f;
    __syncthreads();

    // ===== Phase A: xp0[t] = Wih0 @ x(t) + b_ih0 + b_hh0 (t-parallel) =====
    if (tid < 512) {
        const int ua = tid >> 2, sa = tid & 3;
        float w0[4][16];
        load_rows<16>(Wih0, IN_DIM, ua, sa, w0);
        float bb[4];
        #pragma unroll
        for (int i = 0; i < 4; ++i) bb[i] = bih0[ua + 128 * i] + bhh0[ua + 128 * i];
        const float* xst = &h2h[0][0];
        #pragma unroll 1
        for (int t = 0; t < TLEN; ++t) {
            float acc[4] = {0.f, 0.f, 0.f, 0.f};
            matvec<16>(w0, xst + t * IN_DIM + 16 * sa, acc);
            #pragma unroll
            for (int i = 0; i < 4; ++i) acc[i] = quad_reduce(acc[i]);
            if (sa == 0) {
                #pragma unroll
                for (int i = 0; i < 4; ++i) xp0[t * G4 + 128 * i + ua] = acc[i] + bb[i];
            }
        }
    }
    __syncthreads();

    // ===== pipelined recurrence: 34 barrier steps =====
    float cc = 0.f; // cell state (A: layer 0, C: layer 1; B unused)
    #pragma unroll 1
    for (int tau = 0; tau < TLEN + 2; ++tau) {
        const int rd = (tau + 1) & 1; // slot written last step
        const int wr = tau & 1;
        if (grp == 0) {
            if (tau < TLEN) {
                float acc[4] = {0.f, 0.f, 0.f, 0.f};
                matvec<64>(w, &h1r[rd][68 * s], acc);          // h1(tau-1); tau=0 -> zeros
                #pragma unroll
                for (int i = 0; i < 4; ++i) acc[i] = pair_reduce(acc[i]);
                const float x0 = xp0[tau * G4 + r];
                const float x1 = xp0[tau * G4 + 128 + r];
                const float x2 = xp0[tau * G4 + 256 + r];
                const float x3 = xp0[tau * G4 + 384 + r];
                const float iv = fast_sigmoid(acc[0] + x0);
                const float fv = fast_sigmoid(acc[1] + x1);
                const float gv = fast_tanh(acc[2] + x2);
                const float ov = fast_sigmoid(acc[3] + x3);
                cc = fv * cc + iv * gv;
                const float h = ov * fast_tanh(cc);
                if (s == 0) h1r[wr][roff] = h;                 // publish h1(tau)
            }
        } else if (grp == 1) {
            if (tau >= 1 && tau < TLEN + 1) {
                float acc[4] = {0.f, 0.f, 0.f, 0.f};
                matvec<64>(w, &h1r[rd][68 * s], acc);          // h1(tau-1)
                #pragma unroll
                for (int i = 0; i < 4; ++i) acc[i] = pair_reduce(acc[i]);
                if (s == 0) {
                    #pragma unroll
                    for (int i = 0; i < 4; ++i) pr[wr][128 * i + r] = acc[i] + bi[i]; // p(tau-1)
                }
            }
        } else {
            if (tau >= 2) {
                float acc[4] = {0.f, 0.f, 0.f, 0.f};
                matvec<64>(w, &h2r[rd][68 * s], acc);          // h2(tau-3); tau=2 -> zeros
                #pragma unroll
                for (int i = 0; i < 4; ++i) acc[i] = pair_reduce(acc[i]);
                const float p0 = pr[rd][r];
                const float p1 = pr[rd][128 + r];
                const float p2 = pr[rd][256 + r];
                const float p3 = pr[rd][384 + r];                // p(tau-2)
                const float iv = fast_sigmoid(acc[0] + p0);
                const float fv = fast_sigmoid(acc[1] + p1);
                const float gv = fast_tanh(acc[2] + p2);
                const float ov = fast_sigmoid(acc[3] + p3);
                cc = fv * cc + iv * gv;
                const float h = ov * fast_tanh(cc);
                if (s == 0) {
                    h2r[wr][roff] = h;                          // publish h2(tau-2)
                    h2h[tau - 2][r] = h;                        // history for readout
                }
            }
        }
        __syncthreads();
    }

    // ===== Phase E: y[trace*32+t] = dot(h2(t), W_lin) + b_lin =====
    if (tid < 128) {
        const int tq = tid >> 2;
        const int sq = tid & 3;
        float wl[32];
        #pragma unroll
        for (int j = 0; j < 8; ++j) {
            float4 v = *(const float4*)(Wlin + 32 * sq + 4 * j);
            wl[4 * j + 0] = v.x; wl[4 * j + 1] = v.y;
            wl[4 * j + 2] = v.z; wl[4 * j + 3] = v.w;
        }
        const float* hb = &h2h[tq][32 * sq];
        float a = 0.f;
        #pragma unroll
        for (int j = 0; j < 8; ++j) {
            float4 v = *(const float4*)(hb + 4 * j);
            a = fmaf(v.x, wl[4 * j + 0], a);
            a = fmaf(v.y, wl[4 * j + 1], a);
            a = fmaf(v.z, wl[4 * j + 2], a);
            a = fmaf(v.w, wl[4 * j + 3], a);
        }
        a = quad_reduce(a);
        if (sq == 0) y[trace * TLEN + tq] = a + blin[0];
    }
}

// ---------- launch ----------

extern "C" void kernel_launch(void* const* d_in, const int* in_sizes, int n_in,
                              void* d_out, int out_size, void* d_ws, size_t ws_size,
                              hipStream_t stream) {
    const float* input = (const float*)d_in[0];  // [4096][64]
    const float* W_ih0 = (const float*)d_in[1];  // [512][64]
    const float* W_hh0 = (const float*)d_in[2];  // [512][128]
    const float* b_ih0 = (const float*)d_in[3];  // [512]
    const float* b_hh0 = (const float*)d_in[4];  // [512]
    const float* W_ih1 = (const float*)d_in[5];  // [512][128]
    const float* W_hh1 = (const float*)d_in[6];  // [512][128]
    const float* b_ih1 = (const float*)d_in[7];  // [512]
    const float* b_hh1 = (const float*)d_in[8];  // [512]
    const float* W_lin = (const float*)d_in[9];  // [1][128]
    const float* b_lin = (const float*)d_in[10]; // [1]
    float* out = (float*)d_out;                  // [4096]

    // single kernel, one WG per trace; d_ws unused
    lstm_pipe<<<N_TRACES, 768, 0, stream>>>(input, W_ih0, W_hh0, b_ih0, b_hh0,
                                            W_ih1, W_hh1, b_ih1, b_hh1,
                                            W_lin, b_lin, out);
}

// Round 10
// 168.616 us; speedup vs baseline: 2.7963x; 2.7963x over previous
//
#include <hip/hip_runtime.h>

#define N_TRACES 128
#define TLEN 32
#define IN_DIM 64
#define HID 128
#define G4 512

// ---------- helpers ----------

__device__ __forceinline__ float fast_sigmoid(float x) {
    return 1.0f / (1.0f + __expf(-x));
}
__device__ __forceinline__ float fast_tanh(float x) {
    return 1.0f - 2.0f / (__expf(2.0f * x) + 1.0f);
}
// sum across the 4 lanes of a quad, result in all 4 lanes
__device__ __forceinline__ float quad_reduce(float x) {
    x += __int_as_float(__builtin_amdgcn_update_dpp(
        0, __float_as_int(x), 0xB1 /*quad_perm [1,0,3,2]*/, 0xF, 0xF, true));
    x += __int_as_float(__builtin_amdgcn_update_dpp(
        0, __float_as_int(x), 0x4E /*quad_perm [2,3,0,1]*/, 0xF, 0xF, true));
    return x;
}

// load 4 gate rows {u+128i} of W[512][ld], k-slice [SW*s, SW*s+SW)
template <int SW>
__device__ __forceinline__ void load_rows(const float* __restrict__ W, int ld,
                                          int u, int s, float (&w)[4][SW]) {
    #pragma unroll
    for (int i = 0; i < 4; ++i) {
        const float* wr = W + (size_t)(u + 128 * i) * ld + SW * s;
        #pragma unroll
        for (int j = 0; j < SW / 4; ++j) {
            float4 v = *(const float4*)(wr + 4 * j);
            w[i][4 * j + 0] = v.x; w[i][4 * j + 1] = v.y;
            w[i][4 * j + 2] = v.z; w[i][4 * j + 3] = v.w;
        }
    }
    // forbid rematerialization into the loops (r9: refetch = 705 MB disaster)
    #pragma unroll
    for (int i = 0; i < 4; ++i)
        #pragma unroll
        for (int j = 0; j < SW; ++j)
            asm volatile("" : "+v"(w[i][j]));
}

template <int SW>
__device__ __forceinline__ void matvec(const float (&w)[4][SW],
                                       const float* hb, float (&acc)[4]) {
    #pragma unroll
    for (int j = 0; j < SW / 4; ++j) {
        float4 v = *(const float4*)(hb + 4 * j);
        const float hx[4] = {v.x, v.y, v.z, v.w};
        #pragma unroll
        for (int e = 0; e < 4; ++e) {
            acc[0] = fmaf(w[0][4 * j + e], hx[e], acc[0]);
            acc[1] = fmaf(w[1][4 * j + e], hx[e], acc[1]);
            acc[2] = fmaf(w[2][4 * j + e], hx[e], acc[2]);
            acc[3] = fmaf(w[3][4 * j + e], hx[e], acc[3]);
        }
    }
}

// ---------- single fully-fused kernel: r6's proven phase machine + in-kernel phase A ----------
// 512 threads = 8 waves = 2 waves/SIMD (the ONLY config where a phase's 128
// weight-floats/thread stay on-chip: 2 waves/SIMD -> 256-reg unified budget.
// r9 proved 3 waves/SIMD evicts weights -> 705 MB refetch).
// Thread (u=tid>>2, s=tid&3): gate rows {u+128i}, k-slice [32s,32s+32).
// hs padded p(k)=k+4*(k>>5): slice s at word 36s, conflict-free broadcasts.
// No global memory ops inside any loop (r5/r7/r9: barrier drains vmcnt(0)).

__global__ __launch_bounds__(512) void lstm_all(
    const float* __restrict__ input, // [4096][64]
    const float* __restrict__ Wih0,  // [512][64]
    const float* __restrict__ Whh0,  // [512][128]
    const float* __restrict__ bih0,  // [512]
    const float* __restrict__ bhh0,  // [512]
    const float* __restrict__ Wih1,  // [512][128]
    const float* __restrict__ Whh1,  // [512][128]
    const float* __restrict__ bih1,  // [512]
    const float* __restrict__ bhh1,  // [512]
    const float* __restrict__ Wlin,  // [128]
    const float* __restrict__ blin,  // [1]
    float* __restrict__ y)           // [4096]
{
    const int trace = blockIdx.x;
    const int tid = threadIdx.x;
    const int u = tid >> 2;
    const int s = tid & 3;
    const int pu = u + 4 * (u >> 5); // padded word index for unit u

    __shared__ float xp[TLEN * G4];  // 64 KB: xproj0, later overwritten by xproj1
    __shared__ float hs[TLEN][140];  // 17.5 KB: x staging, then h1, then h2

    // ===== stage this trace's input (2048 floats) into the hs region =====
    {
        const float4* src = (const float4*)(input + (size_t)trace * TLEN * IN_DIM);
        ((float4*)&hs[0][0])[tid] = src[tid];
    }

    // ===== Phase A: xp[t] = Wih0 @ x(t) + b_ih0 + b_hh0 (t-parallel, no inner barrier) =====
    {
        float w0[4][16];
        load_rows<16>(Wih0, IN_DIM, u, s, w0);
        float bb[4];
        #pragma unroll
        for (int i = 0; i < 4; ++i) bb[i] = bih0[u + 128 * i] + bhh0[u + 128 * i];
        __syncthreads(); // x staged
        const float* xst = &hs[0][0];
        #pragma unroll 1
        for (int t = 0; t < TLEN; ++t) {
            float acc[4] = {0.f, 0.f, 0.f, 0.f};
            matvec<16>(w0, xst + t * IN_DIM + 16 * s, acc);
            #pragma unroll
            for (int i = 0; i < 4; ++i) acc[i] = quad_reduce(acc[i]);
            if (s == 0) {
                #pragma unroll
                for (int i = 0; i < 4; ++i) xp[t * G4 + 128 * i + u] = acc[i] + bb[i];
            }
        }
    }
    __syncthreads(); // xp0 ready; hs region free for h1

    // ===== Phase B: layer-0 recurrence (h1 -> hs) =====
    {
        float w[4][32];
        load_rows<32>(Whh0, HID, u, s, w);
        float cc = 0.f;
        #pragma unroll 1
        for (int t = 0; t < TLEN; ++t) {
            const float xg0 = xp[t * G4 + u];
            const float xg1 = xp[t * G4 + 128 + u];
            const float xg2 = xp[t * G4 + 256 + u];
            const float xg3 = xp[t * G4 + 384 + u];
            float acc[4] = {0.f, 0.f, 0.f, 0.f};
            if (t > 0) matvec<32>(w, &hs[t - 1][36 * s], acc);
            #pragma unroll
            for (int i = 0; i < 4; ++i) acc[i] = quad_reduce(acc[i]);
            if (s == 0) {
                const float iv = fast_sigmoid(acc[0] + xg0);
                const float fv = fast_sigmoid(acc[1] + xg1);
                const float gv = fast_tanh(acc[2] + xg2);
                const float ov = fast_sigmoid(acc[3] + xg3);
                cc = fv * cc + iv * gv;
                hs[t][pu] = ov * fast_tanh(cc);
            }
            __syncthreads();
        }
    }

    // ===== Phase C: xp[t] = Wih1 @ h1(t) + b_ih1 + b_hh1 (t-parallel, no inner barrier) =====
    {
        float w[4][32];
        load_rows<32>(Wih1, HID, u, s, w);
        float bi[4];
        #pragma unroll
        for (int i = 0; i < 4; ++i) bi[i] = bih1[u + 128 * i] + bhh1[u + 128 * i];
        #pragma unroll 1
        for (int t = 0; t < TLEN; ++t) {
            float acc[4] = {0.f, 0.f, 0.f, 0.f};
            matvec<32>(w, &hs[t][36 * s], acc);
            #pragma unroll
            for (int i = 0; i < 4; ++i) acc[i] = quad_reduce(acc[i]);
            if (s == 0) {
                #pragma unroll
                for (int i = 0; i < 4; ++i) xp[t * G4 + 128 * i + u] = acc[i] + bi[i];
            }
        }
    }
    __syncthreads(); // xp1 ready; h1 fully consumed

    // ===== Phase D: layer-1 recurrence (h2 overwrites hs) =====
    {
        float w[4][32];
        load_rows<32>(Whh1, HID, u, s, w);
        float cc = 0.f;
        #pragma unroll 1
        for (int t = 0; t < TLEN; ++t) {
            const float xg0 = xp[t * G4 + u];
            const float xg1 = xp[t * G4 + 128 + u];
            const float xg2 = xp[t * G4 + 256 + u];
            const float xg3 = xp[t * G4 + 384 + u];
            float acc[4] = {0.f, 0.f, 0.f, 0.f};
            if (t > 0) matvec<32>(w, &hs[t - 1][36 * s], acc);
            #pragma unroll
            for (int i = 0; i < 4; ++i) acc[i] = quad_reduce(acc[i]);
            if (s == 0) {
                const float iv = fast_sigmoid(acc[0] + xg0);
                const float fv = fast_sigmoid(acc[1] + xg1);
                const float gv = fast_tanh(acc[2] + xg2);
                const float ov = fast_sigmoid(acc[3] + xg3);
                cc = fv * cc + iv * gv;
                hs[t][pu] = ov * fast_tanh(cc);
            }
            __syncthreads();
        }
    }

    // ===== Phase E: y[trace*32+t] = dot(h2(t), W_lin) + b_lin =====
    if (tid < 128) {
        const int tq = tid >> 2;
        const int sq = tid & 3;
        float wl[32];
        #pragma unroll
        for (int j = 0; j < 8; ++j) {
            float4 v = *(const float4*)(Wlin + 32 * sq + 4 * j);
            wl[4 * j + 0] = v.x; wl[4 * j + 1] = v.y;
            wl[4 * j + 2] = v.z; wl[4 * j + 3] = v.w;
        }
        const float* hb = &hs[tq][36 * sq];
        float a = 0.f;
        #pragma unroll
        for (int j = 0; j < 8; ++j) {
            float4 v = *(const float4*)(hb + 4 * j);
            a = fmaf(v.x, wl[4 * j + 0], a);
            a = fmaf(v.y, wl[4 * j + 1], a);
            a = fmaf(v.z, wl[4 * j + 2], a);
            a = fmaf(v.w, wl[4 * j + 3], a);
        }
        a = quad_reduce(a);
        if (sq == 0) y[trace * TLEN + tq] = a + blin[0];
    }
}

// ---------- launch ----------

extern "C" void kernel_launch(void* const* d_in, const int* in_sizes, int n_in,
                              void* d_out, int out_size, void* d_ws, size_t ws_size,
                              hipStream_t stream) {
    const float* input = (const float*)d_in[0];  // [4096][64]
    const float* W_ih0 = (const float*)d_in[1];  // [512][64]
    const float* W_hh0 = (const float*)d_in[2];  // [512][128]
    const float* b_ih0 = (const float*)d_in[3];  // [512]
    const float* b_hh0 = (const float*)d_in[4];  // [512]
    const float* W_ih1 = (const float*)d_in[5];  // [512][128]
    const float* W_hh1 = (const float*)d_in[6];  // [512][128]
    const float* b_ih1 = (const float*)d_in[7];  // [512]
    const float* b_hh1 = (const float*)d_in[8];  // [512]
    const float* W_lin = (const float*)d_in[9];  // [1][128]
    const float* b_lin = (const float*)d_in[10]; // [1]
    float* out = (float*)d_out;                  // [4096]

    // single kernel, one WG per trace; d_ws unused
    lstm_all<<<N_TRACES, 512, 0, stream>>>(input, W_ih0, W_hh0, b_ih0, b_hh0,
                                           W_ih1, W_hh1, b_ih1, b_hh1,
                                           W_lin, b_lin, out);
}